// Round 7
// baseline (195.424 us; speedup 1.0000x reference)
//
#include <hip/hip_runtime.h>

#define TQ 512
#define TK 256
#define BB 8
#define CC 128

// 2*log2(e): projections pre-scaled so exp2(qs+ks) == e^(2(q+k))
#define SCALE2L2E 2.8853900817779268f
#define L2E 1.4426950408889634f

__device__ __forceinline__ float fexp2(float x) { return __builtin_amdgcn_exp2f(x); }
__device__ __forceinline__ float frcp(float x)  { return __builtin_amdgcn_rcpf(x); }

// ---------------- projection GEMM v7 ----------------
// Y(rows x 128) = X(rows x K) @ W(128 x K)^T ; row r -> (t = r/8, b = r%8).
// Block: 8 rows x 128 cols, 128 thr (2 waves); thread = 8 rows x 1 col (c=tid).
// W in LDS ws[c][KC+4]: pitch 36/44 dwords (== 4 mod 8) spreads bank quads for
// b128 publish (KC4/thread) and b128 read (1 per k4). X in LDS xs[8][KC+4],
// read as wave-uniform BROADCAST b128 (negligible LDS BW). Register prefetch
// one KC-chunk ahead; 2 barriers/chunk. No SMEM in the hot loop (lgkmcnt = DS only).
template<int K, int KC, int LAY>
__device__ __forceinline__ void proj_block7(
    const float* __restrict__ X, const float* __restrict__ W,
    float* __restrict__ Y, float scale, int Tdim, int rt, float* lds)
{
    constexpr int KC4 = KC / 4;
    constexpr int NCH = K / KC;
    constexpr int KCP = KC + 4;                  // pitch: 36 or 44 (==4 mod 8)
    constexpr int NXJ = 8 * KC4;                 // X float4 stage jobs
    float* ws = lds;                             // [128][KCP]
    float* xs = lds + 128 * KCP;                 // [8][KCP]

    const int tid = threadIdx.x;                 // 0..127 = col
    const int r0 = rt * 8;
    const int xr = tid / KC4, xj = tid % KC4;

    const float* __restrict__ Wcol = W + tid * K;

    float4 pw[KC4], px;
    auto issue = [&](int kc) {
#pragma unroll
        for (int m = 0; m < KC4; ++m)
            pw[m] = *(const float4*)&Wcol[kc * KC + m * 4];
        if (tid < NXJ)
            px = *(const float4*)&X[(r0 + xr) * K + kc * KC + xj * 4];
    };
    auto publish = [&]() {
#pragma unroll
        for (int m = 0; m < KC4; ++m)
            *(float4*)&ws[tid * KCP + m * 4] = pw[m];
        if (tid < NXJ)
            *(float4*)&xs[xr * KCP + xj * 4] = px;
    };

    float acc[8];
#pragma unroll
    for (int i = 0; i < 8; ++i) acc[i] = 0.f;

    issue(0);
    for (int kc = 0; kc < NCH; ++kc) {
        if (kc) __syncthreads();                 // prev-chunk readers done
        publish();
        __syncthreads();
        if (kc + 1 < NCH) issue(kc + 1);         // in flight under compute
#pragma unroll
        for (int k4 = 0; k4 < KC4; ++k4) {
            const float4 wv = *(const float4*)&ws[tid * KCP + k4 * 4];
            float4 xv[8];
#pragma unroll
            for (int r = 0; r < 8; ++r)
                xv[r] = *(const float4*)&xs[r * KCP + k4 * 4];  // broadcast
#pragma unroll
            for (int r = 0; r < 8; ++r) {
                acc[r] = fmaf(xv[r].x, wv.x, acc[r]);
                acc[r] = fmaf(xv[r].y, wv.y, acc[r]);
                acc[r] = fmaf(xv[r].z, wv.z, acc[r]);
                acc[r] = fmaf(xv[r].w, wv.w, acc[r]);
            }
        }
    }

    // r0 multiple of 8: t = rt uniform, b = i
#pragma unroll
    for (int i = 0; i < 8; ++i) {
        float v = acc[i] * scale;
        if (LAY == 0) Y[(i * Tdim + rt) * CC + tid] = v;
        else          Y[(i * CC + tid) * Tdim + rt] = v;
    }
}

// 1024 blocks: odd ids = Q (512), even ids = KV (256 keys + 256 values),
// interleaved so every CU mixes long KV blocks with short Q blocks.
__global__ __launch_bounds__(128) void proj_v7(
    const float* __restrict__ q_in, const float* __restrict__ Wq, float* __restrict__ qp,
    const float* __restrict__ k_in, const float* __restrict__ Wk, float* __restrict__ kp,
    const float* __restrict__ v_in, const float* __restrict__ Wv, float* __restrict__ vp)
{
    __shared__ float lds[128 * 44 + 8 * 44];
    const int id = blockIdx.x;
    const int idx = id >> 1;
    if (id & 1) {
        proj_block7<80, 40, 0>(q_in, Wq, qp, SCALE2L2E, TQ, idx, lds);
    } else {
        if (idx < 256)
            proj_block7<640, 32, 1>(k_in, Wk, kp, SCALE2L2E, TK, idx, lds);
        else
            proj_block7<640, 32, 0>(v_in, Wv, vp, 1.0f, TK, idx - 256, lds);
    }
}

// ---------------- Kernel 2: scores + softmax (no K staging, no transpose) ----
// Wave = 2 q-rows x 256 k (lane holds k = lane*4+j via one float4/c direct from
// L2-resident kp). No barriers. q/Wvec via uniform s_loads.
__global__ __launch_bounds__(256) void attn_kernel(const float* __restrict__ qp,
                                                   const float* __restrict__ kp,
                                                   const float* __restrict__ Wvec,
                                                   float* __restrict__ attn_out) {
    const int tid = threadIdx.x;
    const int lane = tid & 63;
    const int w = __builtin_amdgcn_readfirstlane(tid >> 6);
    const int b = blockIdx.y;
    const int q0 = blockIdx.x * 8 + w * 2;

    const float* __restrict__ qr0 = qp + (b * TQ + q0) * CC;
    const float* __restrict__ qr1 = qr0 + CC;
    const float* __restrict__ kb = kp + b * CC * TK + lane * 4;

    float sw = Wvec[lane] + Wvec[64 + lane];
#pragma unroll
    for (int m = 32; m >= 1; m >>= 1) sw += __shfl_xor(sw, m, 64);

    float a0[4] = {0.f, 0.f, 0.f, 0.f};
    float a1[4] = {0.f, 0.f, 0.f, 0.f};

#pragma unroll 8
    for (int c = 0; c < CC; ++c) {
        const float4 kf = *(const float4*)&kb[c * TK];
        const float qa = qr0[c];     // s_load (uniform)
        const float qb = qr1[c];     // s_load (uniform)
        const float wc = Wvec[c];    // s_load (uniform)
        float t;
        t = fexp2(qa + kf.x); a0[0] = fmaf(wc, frcp(t + 1.f), a0[0]);
        t = fexp2(qa + kf.y); a0[1] = fmaf(wc, frcp(t + 1.f), a0[1]);
        t = fexp2(qa + kf.z); a0[2] = fmaf(wc, frcp(t + 1.f), a0[2]);
        t = fexp2(qa + kf.w); a0[3] = fmaf(wc, frcp(t + 1.f), a0[3]);
        t = fexp2(qb + kf.x); a1[0] = fmaf(wc, frcp(t + 1.f), a1[0]);
        t = fexp2(qb + kf.y); a1[1] = fmaf(wc, frcp(t + 1.f), a1[1]);
        t = fexp2(qb + kf.z); a1[2] = fmaf(wc, frcp(t + 1.f), a1[2]);
        t = fexp2(qb + kf.w); a1[3] = fmaf(wc, frcp(t + 1.f), a1[3]);
    }

    float sc0[4], sc1[4];
#pragma unroll
    for (int j = 0; j < 4; ++j) {
        sc0[j] = sw - 2.f * a0[j];
        sc1[j] = sw - 2.f * a1[j];
    }

    float m0 = fmaxf(fmaxf(sc0[0], sc0[1]), fmaxf(sc0[2], sc0[3]));
    float m1 = fmaxf(fmaxf(sc1[0], sc1[1]), fmaxf(sc1[2], sc1[3]));
#pragma unroll
    for (int m = 32; m >= 1; m >>= 1) {
        m0 = fmaxf(m0, __shfl_xor(m0, m, 64));
        m1 = fmaxf(m1, __shfl_xor(m1, m, 64));
    }
    float e0[4], e1[4], s0 = 0.f, s1 = 0.f;
#pragma unroll
    for (int j = 0; j < 4; ++j) {
        e0[j] = fexp2((sc0[j] - m0) * L2E); s0 += e0[j];
        e1[j] = fexp2((sc1[j] - m1) * L2E); s1 += e1[j];
    }
#pragma unroll
    for (int m = 32; m >= 1; m >>= 1) {
        s0 += __shfl_xor(s0, m, 64);
        s1 += __shfl_xor(s1, m, 64);
    }
    const float r0 = frcp(s0), r1 = frcp(s1);

    const float4 p0 = make_float4(e0[0] * r0, e0[1] * r0, e0[2] * r0, e0[3] * r0);
    const float4 p1 = make_float4(e1[0] * r1, e1[1] * r1, e1[2] * r1, e1[3] * r1);
    *(float4*)&attn_out[(b * TQ + q0) * TK + lane * 4] = p0;
    *(float4*)&attn_out[(b * TQ + q0 + 1) * TK + lane * 4] = p1;
}

// ---------------- Kernel 3: PV v2 (reads attn_out directly) ----------------
// out[b][c][q] = sum_k p[b][q][k] * v[b][k][c].
// Thread = c (tid&127), half-block = 8 q rows; p rows via wave-uniform s_loads
// (SMEM-only kernel -> lgkmcnt clean), v coalesced per k, 8-fold v reuse.
__global__ __launch_bounds__(256) void pv_kernel(const float* __restrict__ attn,
                                                 const float* __restrict__ vp,
                                                 float* __restrict__ out) {
    const int tid = threadIdx.x;
    const int c = tid & 127;
    const int qh = __builtin_amdgcn_readfirstlane(tid >> 7);
    const int b = blockIdx.y;
    const int q0 = blockIdx.x * 16 + qh * 8;

    const float* __restrict__ vb = vp + b * TK * CC + c;
    const float* __restrict__ p0 = attn + (b * TQ + q0) * TK;   // uniform base

    float acc[8];
#pragma unroll
    for (int i = 0; i < 8; ++i) acc[i] = 0.f;

#pragma unroll 4
    for (int k = 0; k < TK; ++k) {
        const float vv = vb[k * CC];
#pragma unroll
        for (int i = 0; i < 8; ++i)
            acc[i] = fmaf(p0[i * TK + k], vv, acc[i]);   // p via s_load
    }

#pragma unroll
    for (int i = 0; i < 8; ++i)
        out[(b * CC + c) * TQ + q0 + i] = acc[i];
}

extern "C" void kernel_launch(void* const* d_in, const int* in_sizes, int n_in,
                              void* d_out, int out_size, void* d_ws, size_t ws_size,
                              hipStream_t stream) {
    const float* queries = (const float*)d_in[0];
    const float* keys    = (const float*)d_in[1];
    const float* values  = (const float*)d_in[2];
    const float* Wq      = (const float*)d_in[3];
    const float* Wk      = (const float*)d_in[4];
    const float* Wv      = (const float*)d_in[5];
    const float* Wvec    = (const float*)d_in[6];

    float* out  = (float*)d_out;                 // (8,128,512)
    float* attn = out + BB * CC * TQ;            // (8,512,256)

    float* ws = (float*)d_ws;
    float* qp = ws;                    // [b][t][c] 4096*128, scaled by 2*log2e
    float* kp = qp + 4096 * CC;        // [b][c][t] 2048*128, scaled
    float* vp = kp + 2048 * CC;        // [b][t][c] 2048*128

    proj_v7<<<dim3(1024), 128, 0, stream>>>(
        queries, Wq, qp, keys, Wk, kp, values, Wv, vp);
    attn_kernel<<<dim3(64, 8), 256, 0, stream>>>(qp, kp, Wvec, attn);
    pv_kernel<<<dim3(32, 8), 256, 0, stream>>>(attn, vp, out);
}